// Round 4
// baseline (1073.800 us; speedup 1.0000x reference)
//
#include <hip/hip_runtime.h>

// MonoFlangerChorusModule — round 3: chunked wave-parallel recurrence,
// metadata software-pipelined 2 chunks ahead so the only loop-carried
// chain is the LDS buf read->fma->write. One wave per (batch,channel).

constexpr int MAX_MIN = 441;   // int(10/1000*44100 + 0.5)
constexpr int MAX_LFO = 441;
constexpr int D = MAX_MIN + MAX_LFO;   // 882
constexpr int B = 32;
constexpr int C = 2;
constexpr int N = 65536;
constexpr int T = 4096;                // tile length
constexpr int PAD = 128;               // eff=0 pad entries after each tile
constexpr int NT = N / T;              // 16 tiles

__global__ __launch_bounds__(64)
void flanger_pipe(const float* __restrict__ x,        // (B,C,N)
                  const float* __restrict__ mod_sig,  // (B,N)
                  const float* __restrict__ feedback, // (B,)
                  const float* __restrict__ mdwp,     // (B,)
                  const float* __restrict__ widthp,   // (B,)
                  const float* __restrict__ depthp,   // (B,)
                  const float* __restrict__ mixp,     // (B,)
                  float* __restrict__ out)            // (B,C,N)
{
  const int bc   = blockIdx.x;        // b*C + c
  const int b    = bc >> 1;
  const int lane = threadIdx.x;       // 0..63

  __shared__ float buf[D + 2];        // +mirror slot at D
  // per-step metadata: q2 = {p | wi<<10 | eff<<20, frac bits}, qx = x value
  __shared__ uint2 q2[T + PAD];
  __shared__ float qx[T + PAD];

  for (int i = lane; i < D + 2; i += 64) buf[i] = 0.0f;
  for (int i = lane; i < PAD; i += 64) {    // pads: eff=0 -> always invalid
    q2[T + i] = make_uint2(0u, 0u);
    qx[T + i] = 0.0f;
  }

  const float fb     = feedback[b];
  const float dpv    = depthp[b];
  const float mx     = mixp[b];
  const float wscale = (float)MAX_LFO * widthp[b];  // 441*width
  const float dmin   = mdwp[b] * (float)MAX_MIN;    // mdw*441

  const float* __restrict__ xc = x + (size_t)bc * N;
  const float* __restrict__ ms = mod_sig + (size_t)b * N;
  float* __restrict__ oc = out + (size_t)bc * N;

  __syncthreads();

  for (int t = 0; t < NT; ++t) {
    const int tbase = t * T;
    const int tend  = tbase + T;

    // ---- meta phase: per-step {p, wi, eff, frac, x} ----
#pragma unroll 8
    for (int rr = 0; rr < T / 64; ++rr) {
      const int i = rr * 64 + lane;
      const int s = tbase + i;
      const float mv = ms[s];
      const float xv = xc[s];
      const float delay = wscale * mv + dmin;        // [0, 882)
      const int   wi = s % D;
      float r = (float)wi - delay + (float)D;        // (0, 2D)
      if (r >= (float)D) r -= (float)D;              // exact == fmod here
      const float pf = floorf(r);
      const int   p  = (int)pf;                      // 0..881
      const float f  = r - pf;
      int dist = wi - p;
      if (dist <= 0) dist += D;                      // steps since slot p written
      int eff = (dist == 1) ? 1 : (dist - 1);        // min over {p, p+1}, >= 1
      if (eff > 64) eff = 64;
      q2[i] = make_uint2((unsigned)(p | (wi << 10) | (eff << 20)),
                         __float_as_uint(f));
      qx[i] = xv;
    }
    // single wave: DS ops in-order; no barrier needed before serial phase

    // ---- serial phase: chunk pipeline ----
    // state: chunk i meta in (c2,cx), chunk i+1 meta in (n2,nx); K = len(i)
    int s0 = tbase;
    uint2 c2 = q2[lane];
    float cx = qx[lane];
    {
      const int effc = (int)(c2.x >> 20);
      const unsigned long long bad = __ballot(effc <= lane);
      int K = bad ? (int)__ffsll((long long)bad) - 1 : 64;
      int s1 = s0 + K;
      uint2 n2 = q2[s1 - tbase + lane];
      float nx = qx[s1 - tbase + lane];

      while (s0 < tend) {
        // buf RMW for chunk i (addresses from regs resolved 2 iters ago)
        const unsigned pw = c2.x;
        const int p  = (int)(pw & 1023u);
        const int wi = (int)((pw >> 10) & 1023u);
        const float frv = __uint_as_float(c2.y);
        const float pv = buf[p];
        const float nv = buf[p + 1];                 // p==881 -> mirror

        // next-next chunk bookkeeping (uses only registers)
        const int effn = (int)(n2.x >> 20);
        const unsigned long long badn = __ballot(effn <= lane);
        const int K1 = badn ? (int)__ffsll((long long)badn) - 1 : 64;
        const int s2 = s1 + K1;

        // prefetch chunk i+2 metadata (latency hidden: used next iter)
        const uint2 f2 = q2[s2 - tbase + lane];
        const float fx = qx[s2 - tbase + lane];

        const float interp = frv * nv + (1.0f - frv) * pv;
        const float xv = cx;
        const float y  = xv + fb * interp;
        if (lane < K) {
          buf[wi] = y;
          buf[(wi == 0) ? D : wi] = y;               // branchless mirror
          const float o = xv + dpv * interp;
          float res = (1.0f - mx) * xv + mx * o;
          res = fminf(fmaxf(res, -1.0f), 1.0f);
          oc[s0 + lane] = res;
        }

        // rotate pipeline
        s0 = s1; K = K1; s1 = s2;
        c2 = n2; cx = nx;
        n2 = f2; nx = fx;
      }
    }
    __syncthreads();   // drain before q2 is overwritten next tile
  }
}

extern "C" void kernel_launch(void* const* d_in, const int* in_sizes, int n_in,
                              void* d_out, int out_size, void* d_ws, size_t ws_size,
                              hipStream_t stream) {
  const float* x        = (const float*)d_in[0];
  const float* mod_sig  = (const float*)d_in[1];
  const float* feedback = (const float*)d_in[2];
  const float* mdw      = (const float*)d_in[3];
  const float* width    = (const float*)d_in[4];
  const float* depth    = (const float*)d_in[5];
  const float* mix      = (const float*)d_in[6];
  float* out = (float*)d_out;

  flanger_pipe<<<dim3(B * C), dim3(64), 0, stream>>>(
      x, mod_sig, feedback, mdw, width, depth, mix, out);
}

// Round 5
// 796.128 us; speedup vs baseline: 1.3488x; 1.3488x over previous
//
#include <hip/hip_runtime.h>

// MonoFlangerChorusModule — round 4: minimal serial loop.
// One wave per (batch,channel). Meta phase precomputes per step:
//   {p, n=(p+1)%D, eff} packed + frac + x + wi  (one uint4, one ds_read_b128)
// Serial loop: 1 b128 read (next meta) + 2 b32 buf reads + 3 fma +
// 1 cndmask + 2 ds_writes + ballot. No exec juggling, no global stores,
// no mirror maintenance. Parallel epilogue does mix/clip/store.

constexpr int MAX_MIN = 441;   // int(10/1000*44100 + 0.5)
constexpr int MAX_LFO = 441;
constexpr int D = MAX_MIN + MAX_LFO;   // 882
constexpr int B = 32;
constexpr int C = 2;
constexpr int N = 65536;
constexpr int T = 2048;                // tile length
constexpr int PAD = 128;               // eff=0 pad entries after each tile
constexpr int NT = N / T;

__global__ __launch_bounds__(64)
void flanger_lean(const float* __restrict__ x,        // (B,C,N)
                  const float* __restrict__ mod_sig,  // (B,N)
                  const float* __restrict__ feedback, // (B,)
                  const float* __restrict__ mdwp,     // (B,)
                  const float* __restrict__ widthp,   // (B,)
                  const float* __restrict__ depthp,   // (B,)
                  const float* __restrict__ mixp,     // (B,)
                  float* __restrict__ out)            // (B,C,N)
{
  const int bc   = blockIdx.x;        // b*C + c
  const int b    = bc >> 1;
  const int lane = threadIdx.x;       // 0..63

  __shared__ float buf[D + 64];       // [D, D+64) = per-lane dump slots
  __shared__ uint4 q[T + PAD];        // {p | n<<12 | eff<<24, frac, x, wi}
  __shared__ float it[T + PAD];       // interp per step (+overshoot room)

  for (int i = lane; i < D + 64; i += 64) buf[i] = 0.0f;
  for (int i = lane; i < PAD; i += 64)
    q[T + i] = make_uint4(0u, 0u, 0u, 0u);   // eff=0 -> chunks stop at tile end
  // single wave: DS ops are in program order; no barriers needed anywhere

  const float fb     = feedback[b];
  const float dpv    = depthp[b];
  const float mx     = mixp[b];
  const float wscale = (float)MAX_LFO * widthp[b];  // 441*width
  const float dmin   = mdwp[b] * (float)MAX_MIN;    // mdw*441

  const float* __restrict__ xc = x + (size_t)bc * N;
  const float* __restrict__ ms = mod_sig + (size_t)b * N;
  float* __restrict__ oc = out + (size_t)bc * N;

  const int dumpi = D + lane;         // this lane's dump slot

  for (int t = 0; t < NT; ++t) {
    const int tbase = t * T;
    const int tend  = tbase + T;

    // ---- meta phase (parallel) ----
#pragma unroll 8
    for (int rr = 0; rr < T / 64; ++rr) {
      const int i = rr * 64 + lane;
      const int s = tbase + i;
      const float mv = ms[s];
      const float xv = xc[s];
      const float delay = wscale * mv + dmin;        // [0, 882)
      const int   wi = s % D;
      float r = (float)wi - delay + (float)D;        // (0, 2D)
      if (r >= (float)D) r -= (float)D;              // exact == fmod here
      const float pf = floorf(r);
      const int   p  = (int)pf;                      // 0..881
      const float f  = r - pf;
      const int   nn = (p + 1 == D) ? 0 : p + 1;     // wrap precomputed
      int dist = wi - p;
      if (dist <= 0) dist += D;                      // steps since p written
      int eff = (dist == 1) ? 1 : dist - 1;          // dep bound, >= 1
      if (eff > 64) eff = 64;
      q[i] = make_uint4((unsigned)p | ((unsigned)nn << 12) | ((unsigned)eff << 24),
                        __float_as_uint(f), __float_as_uint(xv), (unsigned)wi);
    }

    // ---- serial phase: chunked recurrence, minimal body ----
    {
      int s0 = tbase;
      uint4 c = q[lane];                             // meta(chunk 0)
      int K;
      {
        const unsigned long long bad = __ballot((int)(c.x >> 24) <= lane);
        K = bad ? (int)__ffsll((long long)bad) - 1 : 64;
      }
      int s1 = s0 + K;

      while (s0 < tend) {
        const uint4 n = q[s1 - tbase + lane];        // meta(next chunk)

        const int p4 = (int)(c.x & 0xfffu);
        const int n4 = (int)((c.x >> 12) & 0xfffu);
        const float pv = buf[p4];
        const float nv = buf[n4];
        const float f  = __uint_as_float(c.y);
        const float xv = __uint_as_float(c.z);
        const float interp = f * nv + (1.0f - f) * pv;
        const float y = xv + fb * interp;

        const int wa = (lane < K) ? (int)c.w : dumpi;   // branchless mask
        buf[wa] = y;
        it[s0 - tbase + lane] = interp;              // unmasked: retiring
                                                     // chunk's write is last
        const unsigned long long bad = __ballot((int)(n.x >> 24) <= lane);
        int K1 = bad ? (int)__ffsll((long long)bad) - 1 : 64;
        const int s2 = s1 + K1;

        c = n; K = K1; s0 = s1; s1 = s2;
      }
    }

    // ---- epilogue (parallel): mix + clip + store ----
#pragma unroll 4
    for (int rr = 0; rr < T / 64; ++rr) {
      const int i = rr * 64 + lane;
      const float xv = __uint_as_float(q[i].z);
      const float interp = it[i];
      const float o = xv + dpv * interp;
      float res = (1.0f - mx) * xv + mx * o;
      res = fminf(fmaxf(res, -1.0f), 1.0f);
      oc[tbase + i] = res;
    }
  }
}

extern "C" void kernel_launch(void* const* d_in, const int* in_sizes, int n_in,
                              void* d_out, int out_size, void* d_ws, size_t ws_size,
                              hipStream_t stream) {
  const float* x        = (const float*)d_in[0];
  const float* mod_sig  = (const float*)d_in[1];
  const float* feedback = (const float*)d_in[2];
  const float* mdw      = (const float*)d_in[3];
  const float* width    = (const float*)d_in[4];
  const float* depth    = (const float*)d_in[5];
  const float* mix      = (const float*)d_in[6];
  float* out = (float*)d_out;

  flanger_lean<<<dim3(B * C), dim3(64), 0, stream>>>(
      x, mod_sig, feedback, mdw, width, depth, mix, out);
}

// Round 6
// 629.017 us; speedup vs baseline: 1.7071x; 1.2657x over previous
//
#include <hip/hip_runtime.h>

// MonoFlangerChorusModule — round 5: producer/consumer wave pipeline.
// Block = 4 waves per (batch,channel) chain; barrier-stepped tile intervals.
//  wave0: consumer — pure LDS buf RMW loop, chunk starts precomputed.
//  wave1/2: per-half eff compute (tile v) + ballot orbit scan (tile v-1).
//  wave3: q metadata build (tile v-3) + epilogue mix/clip/store (tile v-5).

constexpr int MAX_MIN = 441;   // int(10/1000*44100 + 0.5)
constexpr int MAX_LFO = 441;
constexpr int D = MAX_MIN + MAX_LFO;   // 882
constexpr int B = 32;
constexpr int C = 2;
constexpr int N = 65536;
constexpr int T = 1024;                // tile length
constexpr int H = T / 2;               // half-tile (independent scan unit)
constexpr int NT = N / T;              // 64 tiles
constexpr int MAXCH = H + 2;           // chunk starts per half + sentinel

__global__ __launch_bounds__(256)
void flanger_pc(const float* __restrict__ x,        // (B,C,N)
                const float* __restrict__ mod_sig,  // (B,N)
                const float* __restrict__ feedback, // (B,)
                const float* __restrict__ mdwp,     // (B,)
                const float* __restrict__ widthp,   // (B,)
                const float* __restrict__ depthp,   // (B,)
                const float* __restrict__ mixp,     // (B,)
                float* __restrict__ out)            // (B,C,N)
{
  const int bc   = blockIdx.x;        // b*C + c
  const int b    = bc >> 1;
  const int tid  = threadIdx.x;
  const int wv   = tid >> 6;          // wave id 0..3
  const int lane = tid & 63;

  __shared__ float buf[D + 64];                     // + per-lane dump slots
  __shared__ uint4 qr[2][T + 64];                   // {p|n<<10|wi<<20, frac, x, 0}
  __shared__ float itr[2][T + 64];                  // interp ring (+overshoot)
  __shared__ unsigned short effr[2][2][H + 64];     // [slot][half][pos], pads=0
  __shared__ unsigned short startsr[4][2][MAXCH];   // tile-relative chunk starts
  __shared__ int nchr[4][2];

  if (wv == 0) {
    for (int i = lane; i < D + 64; i += 64) buf[i] = 0.0f;
  } else if (wv == 1) {               // static eff pads (never rewritten)
    effr[0][0][H + lane] = 0; effr[0][1][H + lane] = 0;
    effr[1][0][H + lane] = 0; effr[1][1][H + lane] = 0;
  } else if (wv == 2) {               // static q pads (last-chunk overshoot)
    qr[0][T + lane] = make_uint4(0u, 0u, 0u, 0u);
    qr[1][T + lane] = make_uint4(0u, 0u, 0u, 0u);
  }

  const float fb     = feedback[b];
  const float dpv    = depthp[b];
  const float mx     = mixp[b];
  const float wscale = (float)MAX_LFO * widthp[b];  // 441*width
  const float dmin   = mdwp[b] * (float)MAX_MIN;    // mdw*441

  const float* __restrict__ xc = x + (size_t)bc * N;
  const float* __restrict__ ms = mod_sig + (size_t)b * N;
  float* __restrict__ oc = out + (size_t)bc * N;

  __syncthreads();

  for (int v = 0; v <= NT + 4; ++v) {
    if (wv == 0) {
      // ---------------- consumer: tile t = v-4 ----------------
      const int t = v - 4;
      if (t >= 0 && t < NT) {
        const uint4* __restrict__ q  = qr[t & 1];
        float*       __restrict__ it = itr[t & 1];
        const int slot = t & 3;
        for (int h = 0; h < 2; ++h) {
          const int nch = nchr[slot][h];             // >= 1 always
          const unsigned short* __restrict__ st = startsr[slot][h];
          int s0 = st[0];                            // == h*H
          int s1 = st[1];                            // sentinel if nch==1
          uint4 c = q[s0 + lane];
          for (int k = 0; k < nch; ++k) {
            const int k2 = (k + 2 < nch) ? (k + 2) : nch;
            const int s2 = st[k2];                   // prefetch (broadcast)
            const uint4 nx = q[s1 + lane];           // next chunk meta
            const int K = s1 - s0;                   // exact ballot K
            const unsigned pw = c.x;
            const int p  = (int)(pw & 1023u);
            const int nn = (int)((pw >> 10) & 1023u);
            const int wi = (int)((pw >> 20) & 1023u);
            const float pv = buf[p];
            const float nv = buf[nn];
            const float f  = __uint_as_float(c.y);
            const float xv = __uint_as_float(c.z);
            const float interp = f * nv + (1.0f - f) * pv;
            const float y = xv + fb * interp;
            const int wa = (lane < K) ? wi : (D + lane);  // dump if invalid
            buf[wa] = y;
            it[s0 + lane] = interp;                  // overshoot overwritten later
            c = nx; s0 = s1; s1 = s2;
          }
        }
      }
    } else if (wv <= 2) {
      const int hf = wv - 1;                         // my half
      // ---------- phase A: eff for tile v ----------
      if (v < NT) {
        unsigned short* __restrict__ ef = effr[v & 1][hf];
        const int base = v * T + hf * H;
#pragma unroll
        for (int r = 0; r < H / 64; ++r) {
          const int i = r * 64 + lane;
          const int s = base + i;
          const float mv = ms[s];
          const float delay = wscale * mv + dmin;    // [0, 882)
          const int wi = s % D;
          float rr = (float)wi - delay + (float)D;
          if (rr >= (float)D) rr -= (float)D;
          const int p = (int)floorf(rr);
          int dist = wi - p;
          if (dist <= 0) dist += D;
          int eff = (dist == 1) ? 1 : (dist - 1);
          if (eff > 64) eff = 64;
          ef[i] = (unsigned short)eff;
        }
      }
      // ---------- scan: orbit for tile v-1 ----------
      const int us = v - 1;
      if (us >= 0 && us < NT) {
        const unsigned short* __restrict__ ef = effr[us & 1][hf];
        unsigned short* __restrict__ st = startsr[us & 3][hf];
        int s = 0;
        int k = 0;
        while (s < H) {                              // pads force stop at H
          const int ev = ef[s + lane];
          const unsigned long long bad = __ballot(ev <= lane);
          const int K = bad ? (int)__ffsll((long long)bad) - 1 : 64;
          if (lane == 0) st[k] = (unsigned short)(hf * H + s);
          ++k;
          s += K;
        }
        if (lane == 0) {
          st[k] = (unsigned short)((hf + 1) * H);    // sentinel
          nchr[us & 3][hf] = k;
        }
      }
    } else {
      // ---------- wave3: q build for tile v-3 ----------
      const int uq = v - 3;
      if (uq >= 0 && uq < NT) {
        uint4* __restrict__ q = qr[uq & 1];
        const int base = uq * T;
#pragma unroll 4
        for (int r = 0; r < T / 64; ++r) {
          const int i = r * 64 + lane;
          const int s = base + i;
          const float mv = ms[s];
          const float xv = xc[s];
          const float delay = wscale * mv + dmin;
          const int wi = s % D;
          float rr = (float)wi - delay + (float)D;
          if (rr >= (float)D) rr -= (float)D;
          const float pf = floorf(rr);
          const int p = (int)pf;
          const float f = rr - pf;
          const int nn = (p + 1 == D) ? 0 : (p + 1);
          q[i] = make_uint4((unsigned)p | ((unsigned)nn << 10) | ((unsigned)wi << 20),
                            __float_as_uint(f), __float_as_uint(xv), 0u);
        }
      }
      // ---------- epilogue: tile v-5 ----------
      const int ue = v - 5;
      if (ue >= 0 && ue < NT) {
        const float* __restrict__ it = itr[ue & 1];
        const int base = ue * T;
#pragma unroll 4
        for (int r = 0; r < T / 64; ++r) {
          const int i = r * 64 + lane;
          const float xv = xc[base + i];             // re-read (L2-hot)
          const float interp = it[i];
          const float o = xv + dpv * interp;
          float res = (1.0f - mx) * xv + mx * o;
          res = fminf(fmaxf(res, -1.0f), 1.0f);
          oc[base + i] = res;
        }
      }
    }
    __syncthreads();   // interval boundary: publishes all ring writes
  }
}

extern "C" void kernel_launch(void* const* d_in, const int* in_sizes, int n_in,
                              void* d_out, int out_size, void* d_ws, size_t ws_size,
                              hipStream_t stream) {
  const float* x        = (const float*)d_in[0];
  const float* mod_sig  = (const float*)d_in[1];
  const float* feedback = (const float*)d_in[2];
  const float* mdw      = (const float*)d_in[3];
  const float* width    = (const float*)d_in[4];
  const float* depth    = (const float*)d_in[5];
  const float* mix      = (const float*)d_in[6];
  float* out = (float*)d_out;

  flanger_pc<<<dim3(B * C), dim3(256), 0, stream>>>(
      x, mod_sig, feedback, mdw, width, depth, mix, out);
}